// Round 1
// baseline (70.351 us; speedup 1.0000x reference)
//
#include <hip/hip_runtime.h>
#include <math.h>

#define U 50
#define GATES 200   // 4*U
#define NFEAT 4
#define TT 100
#define BB 256

__device__ __forceinline__ float sigmoid_fast(float x) {
    // 1/(1+exp(-x)); exp overflow -> inf -> 0; underflow -> 0 -> 1. No NaN.
    return 1.0f / (1.0f + __expf(-x));
}

__device__ __forceinline__ float tanh_fast(float x) {
    // tanh(x) = 1 - 2/(exp(2x)+1); exp overflow -> inf -> 1; underflow -> -1. No NaN.
    float e = __expf(2.0f * x);
    return 1.0f - 2.0f / (e + 1.0f);
}

__device__ __forceinline__ float param_act(float x, float mn, float mx) {
    float scale = 0.5f * (mx - mn);
    return tanh_fast(x) * scale + mn + scale;
}

__global__ __launch_bounds__(256) void encoder_kernel(
    const float* __restrict__ x,        // (B,T,4)
    const float* __restrict__ state,    // (B,T,4)
    const float* __restrict__ kernel,   // (4,200)
    const float* __restrict__ rec,      // (50,200)
    const float* __restrict__ bias,     // (200,)
    const float* __restrict__ w_dv, const float* __restrict__ b_dv,
    const float* __restrict__ w_dt, const float* __restrict__ b_dt,
    const float* __restrict__ w_mj, const float* __restrict__ b_mj,
    const float* __restrict__ w_ma, const float* __restrict__ b_ma,
    const float* __restrict__ w_mi, const float* __restrict__ b_mi,
    float* __restrict__ out)            // act_seq (B*T) then idm (B*5)
{
    const int b   = blockIdx.x;
    const int tid = threadIdx.x;

    __shared__ float h_lds[U];
    __shared__ float z_lds[GATES];
    __shared__ float idm[8];

    // Per-thread column registers (threads 0..199 active for the GEMV part)
    float recc[U];
    float kc[NFEAT];
    float bg = 0.0f;
    if (tid < GATES) {
        #pragma unroll
        for (int j = 0; j < U; ++j) recc[j] = rec[j * GATES + tid];
        #pragma unroll
        for (int f = 0; f < NFEAT; ++f) kc[f] = kernel[f * GATES + tid];
        bg = bias[tid];
    }
    if (tid < U) h_lds[tid] = 0.0f;
    float c = 0.0f;
    __syncthreads();

    const float* xb = x + (size_t)b * TT * NFEAT;

    for (int t = 0; t < TT; ++t) {
        if (tid < GATES) {
            // block-uniform x loads (compiler -> s_load)
            float x0 = xb[t * 4 + 0];
            float x1 = xb[t * 4 + 1];
            float x2 = xb[t * 4 + 2];
            float x3 = xb[t * 4 + 3];
            float z = bg + x0 * kc[0] + x1 * kc[1] + x2 * kc[2] + x3 * kc[3];

            float a0 = 0.f, a1 = 0.f, a2 = 0.f, a3 = 0.f;
            #pragma unroll
            for (int j = 0; j < 48; j += 4) {
                a0 += h_lds[j + 0] * recc[j + 0];
                a1 += h_lds[j + 1] * recc[j + 1];
                a2 += h_lds[j + 2] * recc[j + 2];
                a3 += h_lds[j + 3] * recc[j + 3];
            }
            a0 += h_lds[48] * recc[48];
            a1 += h_lds[49] * recc[49];
            z += (a0 + a1) + (a2 + a3);
            z_lds[tid] = z;
        }
        __syncthreads();
        if (tid < U) {
            float zi = z_lds[tid];
            float zf = z_lds[tid + U];
            float zg = z_lds[tid + 2 * U];
            float zo = z_lds[tid + 3 * U];
            float ig = sigmoid_fast(zi);
            float fg = sigmoid_fast(zf);
            float gg = tanh_fast(zg);
            float og = sigmoid_fast(zo);
            c = fg * c + ig * gg;
            float hnew = og * tanh_fast(c);
            h_lds[tid] = hnew;
        }
        __syncthreads();
    }

    // 5 output heads: dot(h, w) + b, then activations
    if (tid < 5) {
        const float* w = (tid == 0) ? w_dv : (tid == 1) ? w_dt :
                         (tid == 2) ? w_mj : (tid == 3) ? w_ma : w_mi;
        const float* bb = (tid == 0) ? b_dv : (tid == 1) ? b_dt :
                          (tid == 2) ? b_mj : (tid == 3) ? b_ma : b_mi;
        float s = bb[0];
        #pragma unroll
        for (int j = 0; j < U; ++j) s += h_lds[j] * w[j];
        float v;
        if (tid == 0)      v = param_act(s, 15.0f, 35.0f);
        else if (tid == 1) v = param_act(s, 0.5f, 3.0f);
        else if (tid == 2) v = fmaxf(s, 0.0f);
        else if (tid == 3) v = param_act(s, 0.5f, 3.0f);
        else               v = param_act(s, 0.5f, 4.0f);
        idm[tid] = v;
        out[BB * TT + b * 5 + tid] = v;
    }
    __syncthreads();

    // IDM physics over the T sequence (parallel across threads)
    const float desired_v    = idm[0];
    const float desired_tgap = idm[1];
    const float min_jamx     = idm[2];
    const float max_act      = idm[3];
    const float min_act      = idm[4];
    const float inv_tsab = 1.0f / (2.0f * sqrtf(max_act * min_act));
    const float inv_dv   = 1.0f / desired_v;

    const float4* sb4 = (const float4*)(state + (size_t)b * TT * NFEAT);
    for (int t = tid; t < TT; t += blockDim.x) {
        float4 s4 = sb4[t];
        float vel = s4.x;
        float dv  = s4.z;
        float dx  = s4.w;
        float dgap = min_jamx + desired_tgap * vel + vel * dv * inv_tsab;
        float r1 = vel * inv_dv;
        r1 = r1 * r1;
        r1 = r1 * r1;            // ^4
        float r2 = dgap / dx;
        r2 = r2 * r2;            // ^2
        out[b * TT + t] = max_act * (1.0f - (r1 + r2));
    }
}

extern "C" void kernel_launch(void* const* d_in, const int* in_sizes, int n_in,
                              void* d_out, int out_size, void* d_ws, size_t ws_size,
                              hipStream_t stream) {
    const float* x      = (const float*)d_in[0];
    const float* state  = (const float*)d_in[1];
    const float* kern   = (const float*)d_in[2];
    const float* rec    = (const float*)d_in[3];
    const float* bias   = (const float*)d_in[4];
    const float* w_dv   = (const float*)d_in[5];
    const float* b_dv   = (const float*)d_in[6];
    const float* w_dt   = (const float*)d_in[7];
    const float* b_dt   = (const float*)d_in[8];
    const float* w_mj   = (const float*)d_in[9];
    const float* b_mj   = (const float*)d_in[10];
    const float* w_ma   = (const float*)d_in[11];
    const float* b_ma   = (const float*)d_in[12];
    const float* w_mi   = (const float*)d_in[13];
    const float* b_mi   = (const float*)d_in[14];
    float* out = (float*)d_out;

    encoder_kernel<<<BB, 256, 0, stream>>>(
        x, state, kern, rec, bias,
        w_dv, b_dv, w_dt, b_dt, w_mj, b_mj, w_ma, b_ma, w_mi, b_mi,
        out);
}